// Round 7
// baseline (1035.157 us; speedup 1.0000x reference)
//
#include <hip/hip_runtime.h>
#include <hip/hip_bf16.h>
#include <math.h>

// Problem constants
#define NSQ   12      // b*F sequences
#define LQ    2048    // per-sequence length
#define DIMQ  384
#define DIQ   192     // d_in
#define RKQ   24      // dt rank
#define NCHK  16      // scan chunks
#define CLEN  128     // chunk length (LQ/NCHK)

// GEMM tiling
#define BM 128
#define BN 64
#define BK 64

typedef unsigned short u16;
typedef __attribute__((ext_vector_type(8))) short s16x8;
typedef __attribute__((ext_vector_type(4))) float f32x4;
typedef __attribute__((ext_vector_type(4))) unsigned short u16x4;
typedef __attribute__((ext_vector_type(8))) unsigned short u16x8;

__device__ __forceinline__ float siluf(float x) {
  return x / (1.0f + __expf(-x));
}
__device__ __forceinline__ float softplusf(float x) {
  return (x > 20.0f) ? x : log1pf(expf(x));
}
__device__ __forceinline__ u16 f2bf(float f) {   // RNE f32->bf16
  unsigned int u = __float_as_uint(f);
  u += 0x7FFFu + ((u >> 16) & 1u);
  return (u16)(u >> 16);
}
__device__ __forceinline__ float bf2f(u16 h) {
  return __uint_as_float(((unsigned int)h) << 16);
}

union F4 { float4 v; float a[4]; };

// VALU-only 16-lane rotation-add (DPP row_ror). All lanes end with the sum.
template<int CTRL>
__device__ __forceinline__ float dpp_add(float x) {
  union { float f; int i; } u, r;
  u.f = x;
  r.i = __builtin_amdgcn_update_dpp(0, u.i, CTRL, 0xF, 0xF, true);
  return x + r.f;
}

// ---------------------------------------------------------------------------
// K0: weight prep. winb/woutb = bf16 GEMM weights. Wcomb (224x192) =
// [dtw @ xpw[:24] ; xpw[24:56]] split into hi/lo bf16 for split-bf16 MFMA.
__global__ void k_prep(const float* __restrict__ xpw, const float* __restrict__ dtw,
                       const float* __restrict__ inw, const float* __restrict__ outw,
                       u16* __restrict__ winb, u16* __restrict__ woutb,
                       u16* __restrict__ wc_hi, u16* __restrict__ wc_lo) {
  int t = threadIdx.x + blockIdx.x * blockDim.x;
  int stride = blockDim.x * gridDim.x;
  for (int i = t; i < DIMQ * DIMQ; i += stride) {
    winb[i]  = f2bf(inw[i]);
    woutb[i] = f2bf(outw[i]);
  }
  for (int i = t; i < 224 * 192; i += stride) {
    const int r = i / 192, k = i % 192;
    float v;
    if (r < 192) {            // W_eff[r][k] = sum_q dtw[r][q]*xpw[q][k]
      float s = 0.0f;
      for (int q = 0; q < RKQ; ++q) s = fmaf(dtw[r * RKQ + q], xpw[q * 192 + k], s);
      v = s;
    } else {
      v = xpw[(24 + (r - 192)) * 192 + k];
    }
    const u16 hi = f2bf(v);
    wc_hi[i] = hi;
    wc_lo[i] = f2bf(v - bf2f(hi));
  }
}

// K0b: zero the scan sync area (ticket counters + flags). Re-run every launch
// because d_ws is re-poisoned before each timed call.
__global__ void k_init(int* __restrict__ sync) {
  const int i = blockIdx.x * 256 + threadIdx.x;
  if (i < 64 + 4608) sync[i] = 0;
}

// ---------------------------------------------------------------------------
// K1: in_proj GEMM via MFMA bf16. Output channel-major xp_t.
__launch_bounds__(256)
__global__ void k_inproj(const float* __restrict__ x, const u16* __restrict__ wbf,
                         const float* __restrict__ bias, float* __restrict__ xp_t) {
  __shared__ __align__(16) char smem[33792];
  u16 (*As)[72] = (u16(*)[72])smem;                 // [128][72]
  u16 (*Bs)[72] = (u16(*)[72])(smem + 18432);       // [64][72]
  const int t = threadIdx.x;
  const int m0 = blockIdx.x * BM;
  const int n0 = blockIdx.y * BN;
  const int lane = t & 63, wid = t >> 6;
  const int wm = wid >> 1, wn = wid & 1;
  const int lr = lane & 15, lg = lane >> 4;
  f32x4 acc[4][2];
#pragma unroll
  for (int i = 0; i < 4; ++i)
#pragma unroll
    for (int j = 0; j < 2; ++j) acc[i][j] = (f32x4){0.f, 0.f, 0.f, 0.f};

  for (int k0 = 0; k0 < 384; k0 += BK) {
    float4 a_ld[8];
#pragma unroll
    for (int i = 0; i < 8; ++i) {
      const int idx = t + i * 256;
      const int row = idx >> 4, kq = (idx & 15) * 4;
      a_ld[i] = *(const float4*)&x[(size_t)(m0 + row) * 384 + k0 + kq];
    }
    u16x8 b_ld[2];
#pragma unroll
    for (int i = 0; i < 2; ++i) {
      const int idx = t + i * 256;
      const int n = idx >> 3, kq = (idx & 7) * 8;
      b_ld[i] = *(const u16x8*)&wbf[(size_t)(n0 + n) * 384 + k0 + kq];
    }
    __syncthreads();
#pragma unroll
    for (int i = 0; i < 8; ++i) {
      const int idx = t + i * 256;
      const int row = idx >> 4, kq = (idx & 15) * 4;
      u16x4 p;
      p.x = f2bf(a_ld[i].x); p.y = f2bf(a_ld[i].y);
      p.z = f2bf(a_ld[i].z); p.w = f2bf(a_ld[i].w);
      *(u16x4*)&As[row][kq] = p;
    }
#pragma unroll
    for (int i = 0; i < 2; ++i) {
      const int idx = t + i * 256;
      const int n = idx >> 3, kq = (idx & 7) * 8;
      *(u16x8*)&Bs[n][kq] = b_ld[i];
    }
    __syncthreads();
#pragma unroll
    for (int kh = 0; kh < BK; kh += 32) {
      s16x8 af[4], bf[2];
#pragma unroll
      for (int mi = 0; mi < 4; ++mi)
        af[mi] = *(const s16x8*)&As[wm * 64 + mi * 16 + lr][kh + lg * 8];
#pragma unroll
      for (int ni = 0; ni < 2; ++ni)
        bf[ni] = *(const s16x8*)&Bs[wn * 32 + ni * 16 + lr][kh + lg * 8];
#pragma unroll
      for (int mi = 0; mi < 4; ++mi)
#pragma unroll
        for (int ni = 0; ni < 2; ++ni)
          acc[mi][ni] = __builtin_amdgcn_mfma_f32_16x16x32_bf16(af[mi], bf[ni], acc[mi][ni], 0, 0, 0);
    }
    __syncthreads();
  }
  float (*T)[132] = (float(*)[132])smem;            // [64][132]
#pragma unroll
  for (int mi = 0; mi < 4; ++mi)
#pragma unroll
    for (int ni = 0; ni < 2; ++ni) {
      const int c_loc = wn * 32 + ni * 16 + lr;
      const int m_loc = wm * 64 + mi * 16 + lg * 4;
      *(f32x4*)&T[c_loc][m_loc] = acc[mi][ni];
    }
  __syncthreads();
  const int s = m0 >> 11, p0 = m0 & 2047;
#pragma unroll
  for (int i = 0; i < 8; ++i) {
    const int idx = t + i * 256;
    const int c = idx >> 5, pq = (idx & 31) * 4;
    float4 v = *(const float4*)&T[c][pq];
    const float bv = bias[n0 + c];
    v.x += bv; v.y += bv; v.z += bv; v.w += bv;
    *(float4*)&xp_t[((size_t)s * 384 + n0 + c) * 2048 + p0 + pq] = v;
  }
}

// ---------------------------------------------------------------------------
// K2: grouped conv (k=3, SAME) + SiLU.
__global__ void k_conv(const float* __restrict__ xp_t, const float* __restrict__ cw,
                       const float* __restrict__ cb, float* __restrict__ xc) {
  const int idx = blockIdx.x * 256 + threadIdx.x;
  const int p = idx & 2047;
  const int sd = idx >> 11;
  const int d = sd % DIQ, s = sd / DIQ;
  const float* r0 = &xp_t[((size_t)s * 384 + 2 * d) * 2048];
  const float* r1 = r0 + 2048;
  const float w00 = cw[d * 6 + 0], w01 = cw[d * 6 + 1], w02 = cw[d * 6 + 2];
  const float w10 = cw[d * 6 + 3], w11 = cw[d * 6 + 4], w12 = cw[d * 6 + 5];
  float acc = cb[d];
  if (p > 0)    acc += w00 * r0[p - 1] + w10 * r1[p - 1];
  acc += w01 * r0[p] + w11 * r1[p];
  if (p < 2047) acc += w02 * r0[p + 1] + w12 * r1[p + 1];
  xc[idx] = siluf(acc);
}

// ---------------------------------------------------------------------------
// K3: fused x_proj + dt_proj as ONE split-bf16 MFMA GEMM.
__launch_bounds__(256)
__global__ void k_xproj(const float* __restrict__ xc, const u16* __restrict__ wc_hi,
                        const u16* __restrict__ wc_lo, const float* __restrict__ dtb,
                        float* __restrict__ delta, float* __restrict__ bc) {
  __shared__ u16 Ah[224][40];
  __shared__ u16 Al[224][40];
  __shared__ u16 Bh[64][40];
  __shared__ u16 Bl[64][40];
  const int t = threadIdx.x;
  const int lane = t & 63, w = t >> 6;
  const int ln = lane & 15, lg = lane >> 4;
  const int blk = blockIdx.x;                 // 0..383
  const int s = blk >> 5, l0 = (blk & 31) * 64;
  f32x4 acc[14];
#pragma unroll
  for (int mi = 0; mi < 14; ++mi) acc[mi] = (f32x4){0.f, 0.f, 0.f, 0.f};

  for (int kc = 0; kc < 192; kc += 32) {
    u16x8 wah[4], wal[4];
#pragma unroll
    for (int i = 0; i < 4; ++i) {
      const int idx = t + i * 256;
      if (idx < 896) {
        const int r = idx >> 2, kg = (idx & 3) * 8;
        wah[i] = *(const u16x8*)&wc_hi[(size_t)r * 192 + kc + kg];
        wal[i] = *(const u16x8*)&wc_lo[(size_t)r * 192 + kc + kg];
      }
    }
    float4 uld[2];
#pragma unroll
    for (int i = 0; i < 2; ++i) {
      const int idx = t + i * 256;
      const int k = idx >> 4, lq = (idx & 15) * 4;
      uld[i] = *(const float4*)&xc[((size_t)s * 192 + kc + k) * 2048 + l0 + lq];
    }
    __syncthreads();
#pragma unroll
    for (int i = 0; i < 4; ++i) {
      const int idx = t + i * 256;
      if (idx < 896) {
        const int r = idx >> 2, kg = (idx & 3) * 8;
        *(u16x8*)&Ah[r][kg] = wah[i];
        *(u16x8*)&Al[r][kg] = wal[i];
      }
    }
#pragma unroll
    for (int i = 0; i < 2; ++i) {
      const int idx = t + i * 256;
      const int k = idx >> 4, lq = (idx & 15) * 4;
      F4 v; v.v = uld[i];
#pragma unroll
      for (int j = 0; j < 4; ++j) {
        const float f = v.a[j];
        const u16 hi = f2bf(f);
        Bh[lq + j][k] = hi;
        Bl[lq + j][k] = f2bf(f - bf2f(hi));
      }
    }
    __syncthreads();
    const s16x8 bh = *(const s16x8*)&Bh[w * 16 + ln][lg * 8];
    const s16x8 bl = *(const s16x8*)&Bl[w * 16 + ln][lg * 8];
#pragma unroll
    for (int mi = 0; mi < 14; ++mi) {
      const s16x8 ah = *(const s16x8*)&Ah[mi * 16 + ln][lg * 8];
      const s16x8 al = *(const s16x8*)&Al[mi * 16 + ln][lg * 8];
      acc[mi] = __builtin_amdgcn_mfma_f32_16x16x32_bf16(ah, bh, acc[mi], 0, 0, 0);
      acc[mi] = __builtin_amdgcn_mfma_f32_16x16x32_bf16(al, bh, acc[mi], 0, 0, 0);
      acc[mi] = __builtin_amdgcn_mfma_f32_16x16x32_bf16(ah, bl, acc[mi], 0, 0, 0);
    }
    __syncthreads();
  }
  const int l = l0 + w * 16 + ln;
#pragma unroll
  for (int mi = 0; mi < 12; ++mi) {
    const int r0 = mi * 16 + lg * 4;
#pragma unroll
    for (int j = 0; j < 4; ++j) {
      const int r = r0 + j;
      delta[((size_t)s * 192 + r) * 2048 + l] = softplusf(acc[mi][j] + dtb[r]);
    }
  }
#pragma unroll
  for (int mi = 12; mi < 14; ++mi) {
    const int rr = (mi - 12) * 16 + lg * 4;
    float4 v;
    v.x = acc[mi][0]; v.y = acc[mi][1]; v.z = acc[mi][2]; v.w = acc[mi][3];
    *(float4*)&bc[((size_t)s * 2048 + l) * 32 + rr] = v;
  }
}

// ---------------------------------------------------------------------------
// Fused single-pass scan (A+B+C) with ticket-ordered decoupled lookback.
// Chain = (s,dg) within one DIR; 144 chains x 16 chunks. Ticket assignment
// guarantees a chunk's predecessors hold smaller tickets (=> already running
// or finished), so spin-waiting is deadlock-free regardless of dispatch order.
template<int DIR>
__launch_bounds__(256)
__global__ void k_scan_fused(const float* __restrict__ delta, const float* __restrict__ xc,
                             const float* __restrict__ bc, const float* __restrict__ A_log,
                             const float* __restrict__ Ab_log,
                             float* __restrict__ Gp, float* __restrict__ Hp,
                             int* sync, float* __restrict__ yout) {
  __shared__ float dch[16][132];
  __shared__ float uch[16][132];
  __shared__ float bsn[16][132];   // B transposed [n][l]
  __shared__ float csn[16][132];   // C transposed [n][l]
  __shared__ int s_v;
  const int t = threadIdx.x;
  if (t == 0) s_v = atomicAdd(&sync[DIR], 1);
  __syncthreads();
  const int v = s_v;
  const int chain = v % 144;            // dg + 12*s
  const int tc = v / 144;
  const int dg = chain % 12, s = chain / 12;
  const int dl = t >> 4, n = t & 15;
  const int d = dg * 16 + dl;
  const int base_l = DIR ? (LQ - CLEN * (tc + 1)) : (CLEN * tc);
  const float a = -__expf((DIR ? Ab_log : A_log)[d * 16 + n]);

  // stage delta/u (row-major) and B/C (transposed) into LDS -- once.
  const size_t rb = ((size_t)s * 192 + dg * 16) * 2048 + base_l;
#pragma unroll
  for (int it = 0; it < 2; ++it) {
    const int i = t + it * 256;
    const int row = i >> 5, c4 = (i & 31) * 4;
    *(float4*)&dch[row][c4] = *(const float4*)&delta[rb + (size_t)row * 2048 + c4];
    *(float4*)&uch[row][c4] = *(const float4*)&xc[rb + (size_t)row * 2048 + c4];
  }
  const size_t bb = ((size_t)s * 2048 + base_l) * 32;
#pragma unroll
  for (int it = 0; it < 4; ++it) {
    const int i = t + it * 256;
    const int l = i >> 3, cq = (i & 7) * 4;
    F4 vv; vv.v = *(const float4*)&bc[bb + (size_t)l * 32 + cq];
    if (cq < 16) {
#pragma unroll
      for (int k = 0; k < 4; ++k) bsn[cq + k][l] = vv.a[k];
    } else {
#pragma unroll
      for (int k = 0; k < 4; ++k) csn[cq - 16 + k][l] = vv.a[k];
    }
  }
  __syncthreads();

  // local pass: chunk end-state (zero init) + gain G = exp(a*sum(delta))
  float h = 0.0f, S = 0.0f;
#pragma unroll 4
  for (int qx = 0; qx < 32; ++qx) {
    const int q = DIR ? (31 - qx) : qx;
    const int lq = q * 4;
    F4 d4, u4, b4;
    d4.v = *(const float4*)&dch[dl][lq];
    u4.v = *(const float4*)&uch[dl][lq];
    b4.v = *(const float4*)&bsn[n][lq];
#pragma unroll
    for (int jj = 0; jj < 4; ++jj) {
      const int j = DIR ? (3 - jj) : jj;
      const float dlt = d4.a[j];
      h = fmaf(__expf(a * dlt), h, dlt * u4.a[j] * b4.a[j]);
      S += dlt;
    }
  }
  const float Gv = __expf(a * S);

  int* flags = sync + 64;
  const int sbase = (DIR * 144 + chain) * NCHK;
  if (tc < NCHK - 1) {     // last chunk has no consumer
    Gp[(size_t)(sbase + tc) * 256 + t] = Gv;
    Hp[(size_t)(sbase + tc) * 256 + t] = h;
    __threadfence();
    __syncthreads();
    if (t == 0)
      __hip_atomic_store(&flags[sbase + tc], 1, __ATOMIC_RELEASE, __HIP_MEMORY_SCOPE_AGENT);
  }

  // lookback: h_in = sum_{p<tc} (prod_{p<q<tc} G_q) * hend_p
  float hin = 0.0f;
  if (tc > 0) {
    float mult = 1.0f, carry = 0.0f;
    for (int p = tc - 1; p >= 0; --p) {
      const int ps = sbase + p;
      if (t == 0) {
        int cnt = 0;
        while (__hip_atomic_load(&flags[ps], __ATOMIC_ACQUIRE, __HIP_MEMORY_SCOPE_AGENT) == 0) {
          if (++cnt > (1 << 24)) break;   // bounded: never hang the bench
        }
      }
      __syncthreads();
      const int hb = __hip_atomic_load((const int*)&Hp[(size_t)ps * 256 + t],
                                       __ATOMIC_RELAXED, __HIP_MEMORY_SCOPE_AGENT);
      const int gb = __hip_atomic_load((const int*)&Gp[(size_t)ps * 256 + t],
                                       __ATOMIC_RELAXED, __HIP_MEMORY_SCOPE_AGENT);
      carry = fmaf(mult, __int_as_float(hb), carry);
      mult *= __int_as_float(gb);
    }
    hin = carry;
  }

  // final pass seeded with hin, emit y (DPP rotation reduce over n lanes)
  h = hin;
  float* yrow = &yout[((size_t)s * 192 + d) * 2048 + base_l];
#pragma unroll 2
  for (int ww = 0; ww < 8; ++ww) {
    const int w = DIR ? (7 - ww) : ww;
    float ykeep = 0.0f;
#pragma unroll
    for (int qq = 0; qq < 4; ++qq) {
      const int q = DIR ? (3 - qq) : qq;
      const int lq = w * 16 + q * 4;
      F4 d4, u4, b4, c4;
      d4.v = *(const float4*)&dch[dl][lq];
      u4.v = *(const float4*)&uch[dl][lq];
      b4.v = *(const float4*)&bsn[n][lq];
      c4.v = *(const float4*)&csn[n][lq];
#pragma unroll
      for (int jj = 0; jj < 4; ++jj) {
        const int j = DIR ? (3 - jj) : jj;
        const float dlt = d4.a[j];
        h = fmaf(__expf(a * dlt), h, dlt * u4.a[j] * b4.a[j]);
        float yv = h * c4.a[j];
        yv = dpp_add<0x128>(yv);
        yv = dpp_add<0x124>(yv);
        yv = dpp_add<0x122>(yv);
        yv = dpp_add<0x121>(yv);
        ykeep = (q * 4 + j == n) ? yv : ykeep;
      }
    }
    yrow[w * 16 + n] = ykeep;
  }
}

// ---------------------------------------------------------------------------
// K4b: combine fwd+bwd+2Du || z, transpose to position-major bf16 A-buffer.
#define SWC(l) (((l >> 2) & 7) << 3)
__launch_bounds__(256)
__global__ void k_combine(const float* __restrict__ yf, const float* __restrict__ yb,
                          const float* __restrict__ xc, const float* __restrict__ Dvec,
                          u16* __restrict__ Abuf) {
  __shared__ u16 T[64][72];
  const int t = threadIdx.x;
  const int cg = blockIdx.x;                 // 0..5
  const int s  = blockIdx.y;                 // 0..11
  const int l0 = blockIdx.z * 64;            // 0..31 chunks
  const int c0 = (cg < 3 ? cg : cg - 3) * 64;
#pragma unroll
  for (int i = 0; i < 4; ++i) {
    const int idx = t + i * 256;             // 1024
    const int cr = idx >> 4, lq = (idx & 15) * 4;
    const size_t off = ((size_t)s * 192 + c0 + cr) * 2048 + l0 + lq;
    F4 v;
    if (cg < 3) {
      F4 f, g, u;
      f.v = *(const float4*)&yf[off];
      g.v = *(const float4*)&yb[off];
      u.v = *(const float4*)&xc[off];
      const float dv2 = 2.0f * Dvec[c0 + cr];
#pragma unroll
      for (int j = 0; j < 4; ++j) v.a[j] = f.a[j] + g.a[j] + dv2 * u.a[j];
    } else {
      v.v = *(const float4*)&xc[off];
    }
#pragma unroll
    for (int j = 0; j < 4; ++j) {
      const int l = lq + j;
      T[l][cr ^ SWC(l)] = f2bf(v.a[j]);
    }
  }
  __syncthreads();
  const int ccol = (cg < 3) ? cg * 64 : 192 + (cg - 3) * 64;
#pragma unroll
  for (int i = 0; i < 2; ++i) {
    const int idx = t + i * 256;             // 512
    const int l = idx >> 3, cq = (idx & 7) * 8;
    const u16x8 v = *(const u16x8*)&T[l][cq ^ SWC(l)];
    *(u16x8*)&Abuf[((size_t)s * 2048 + l0 + l) * 384 + ccol + cq] = v;
  }
}

// ---------------------------------------------------------------------------
// K5: out_proj GEMM via MFMA bf16.
__launch_bounds__(256)
__global__ void k_outproj(const u16* __restrict__ Abuf, const u16* __restrict__ wbf,
                          const float* __restrict__ bias, float* __restrict__ out) {
  __shared__ __align__(16) char smem[34816];
  u16 (*As)[72] = (u16(*)[72])smem;                 // [128][72]
  u16 (*Bs)[72] = (u16(*)[72])(smem + 18432);       // [64][72]
  const int t = threadIdx.x;
  const int m0 = blockIdx.x * BM;
  const int n0 = blockIdx.y * BN;
  const int lane = t & 63, wid = t >> 6;
  const int wm = wid >> 1, wn = wid & 1;
  const int lr = lane & 15, lg = lane >> 4;
  f32x4 acc[4][2];
#pragma unroll
  for (int i = 0; i < 4; ++i)
#pragma unroll
    for (int j = 0; j < 2; ++j) acc[i][j] = (f32x4){0.f, 0.f, 0.f, 0.f};

  for (int k0 = 0; k0 < 384; k0 += BK) {
    u16x8 a_ld[4];
#pragma unroll
    for (int i = 0; i < 4; ++i) {
      const int idx = t + i * 256;
      const int row = idx >> 3, kq = (idx & 7) * 8;
      a_ld[i] = *(const u16x8*)&Abuf[(size_t)(m0 + row) * 384 + k0 + kq];
    }
    u16x8 b_ld[2];
#pragma unroll
    for (int i = 0; i < 2; ++i) {
      const int idx = t + i * 256;
      const int n = idx >> 3, kq = (idx & 7) * 8;
      b_ld[i] = *(const u16x8*)&wbf[(size_t)(n0 + n) * 384 + k0 + kq];
    }
    __syncthreads();
#pragma unroll
    for (int i = 0; i < 4; ++i) {
      const int idx = t + i * 256;
      const int row = idx >> 3, kq = (idx & 7) * 8;
      *(u16x8*)&As[row][kq] = a_ld[i];
    }
#pragma unroll
    for (int i = 0; i < 2; ++i) {
      const int idx = t + i * 256;
      const int n = idx >> 3, kq = (idx & 7) * 8;
      *(u16x8*)&Bs[n][kq] = b_ld[i];
    }
    __syncthreads();
#pragma unroll
    for (int kh = 0; kh < BK; kh += 32) {
      s16x8 af[4], bf[2];
#pragma unroll
      for (int mi = 0; mi < 4; ++mi)
        af[mi] = *(const s16x8*)&As[wm * 64 + mi * 16 + lr][kh + lg * 8];
#pragma unroll
      for (int ni = 0; ni < 2; ++ni)
        bf[ni] = *(const s16x8*)&Bs[wn * 32 + ni * 16 + lr][kh + lg * 8];
#pragma unroll
      for (int mi = 0; mi < 4; ++mi)
#pragma unroll
        for (int ni = 0; ni < 2; ++ni)
          acc[mi][ni] = __builtin_amdgcn_mfma_f32_16x16x32_bf16(af[mi], bf[ni], acc[mi][ni], 0, 0, 0);
    }
    __syncthreads();
  }
  float (*T)[68] = (float(*)[68])smem;              // [128][68]
#pragma unroll
  for (int mi = 0; mi < 4; ++mi)
#pragma unroll
    for (int ni = 0; ni < 2; ++ni) {
      const int c_loc = wn * 32 + ni * 16 + lr;
      const int m_loc = wm * 64 + mi * 16 + lg * 4;
#pragma unroll
      for (int r = 0; r < 4; ++r) T[m_loc + r][c_loc] = acc[mi][ni][r];
    }
  __syncthreads();
#pragma unroll
  for (int i = 0; i < 8; ++i) {
    const int idx = t + i * 256;
    const int m = idx >> 4, cq = (idx & 15) * 4;
    float4 v = *(const float4*)&T[m][cq];
    const float4 bb = *(const float4*)&bias[n0 + cq];
    v.x += bb.x; v.y += bb.y; v.z += bb.z; v.w += bb.w;
    *(float4*)&out[(size_t)(m0 + m) * 384 + n0 + cq] = v;
  }
}

// ---------------------------------------------------------------------------
extern "C" void kernel_launch(void* const* d_in, const int* in_sizes, int n_in,
                              void* d_out, int out_size, void* d_ws, size_t ws_size,
                              hipStream_t stream) {
  const float* x     = (const float*)d_in[0];
  const float* inw   = (const float*)d_in[1];
  const float* inb   = (const float*)d_in[2];
  const float* convw = (const float*)d_in[3];
  const float* convb = (const float*)d_in[4];
  const float* alog  = (const float*)d_in[5];
  const float* ablog = (const float*)d_in[6];
  const float* Dv    = (const float*)d_in[7];
  const float* xpw   = (const float*)d_in[8];
  const float* dtw   = (const float*)d_in[9];
  const float* dtb   = (const float*)d_in[10];
  const float* outw  = (const float*)d_in[11];
  const float* outb  = (const float*)d_in[12];
  float* out = (float*)d_out;

  float* ws = (float*)d_ws;
  float* xp_t  = ws;                       // 9437184
  float* xc    = xp_t + 9437184;           // 4718592
  float* delta = xc + 4718592;             // 4718592
  float* bc    = delta + 4718592;          // 786432
  float* G     = bc + 786432;              // 1179648 (publish: gains)
  float* hc    = G + 1179648;              // 1179648 (publish: end states)
  u16*   winb  = (u16*)(hc + 1179648);     // 147456 u16
  u16*   woutb = winb + 147456;            // 147456 u16
  u16*   wc_hi = woutb + 147456;           // 43008 u16
  u16*   wc_lo = wc_hi + 43008;            // 43008 u16
  int*   sync  = (int*)(wc_lo + 43008);    // 64 + 4608 ints
  // yf/yb alias xp_t (dead after conv); Abuf aliases delta (dead after scan)
  float* yf = xp_t;
  float* yb = xp_t + 4718592;
  u16*   Abuf = (u16*)delta;

  hipLaunchKernelGGL(k_prep,         dim3(96),        dim3(256), 0, stream, xpw, dtw, inw, outw, winb, woutb, wc_hi, wc_lo);
  hipLaunchKernelGGL(k_init,         dim3(19),        dim3(256), 0, stream, sync);
  hipLaunchKernelGGL(k_inproj,       dim3(192, 6),    dim3(256), 0, stream, x, winb, inb, xp_t);
  hipLaunchKernelGGL(k_conv,         dim3(18432),     dim3(256), 0, stream, xp_t, convw, convb, xc);
  hipLaunchKernelGGL(k_xproj,        dim3(384),       dim3(256), 0, stream, xc, wc_hi, wc_lo, dtb, delta, bc);
  hipLaunchKernelGGL((k_scan_fused<0>), dim3(2304),   dim3(256), 0, stream, delta, xc, bc, alog, ablog, G, hc, sync, yf);
  hipLaunchKernelGGL((k_scan_fused<1>), dim3(2304),   dim3(256), 0, stream, delta, xc, bc, alog, ablog, G, hc, sync, yb);
  hipLaunchKernelGGL(k_combine,      dim3(6, 12, 32), dim3(256), 0, stream, yf, yb, xc, Dv, Abuf);
  hipLaunchKernelGGL(k_outproj,      dim3(192, 6),    dim3(256), 0, stream, Abuf, woutb, outb, out);
}

// Round 8
// 331.471 us; speedup vs baseline: 3.1229x; 3.1229x over previous
//
#include <hip/hip_runtime.h>
#include <hip/hip_bf16.h>
#include <math.h>

// Problem constants
#define NSQ   12      // b*F sequences
#define LQ    2048    // per-sequence length
#define DIMQ  384
#define DIQ   192     // d_in
#define RKQ   24      // dt rank
#define NCHK  16      // scan chunks
#define CLEN  128     // chunk length (LQ/NCHK)

// GEMM tiling
#define BM 128
#define BN 64
#define BK 64

typedef unsigned short u16;
typedef __attribute__((ext_vector_type(8))) short s16x8;
typedef __attribute__((ext_vector_type(4))) float f32x4;
typedef __attribute__((ext_vector_type(4))) unsigned short u16x4;
typedef __attribute__((ext_vector_type(8))) unsigned short u16x8;

__device__ __forceinline__ float siluf(float x) {
  return x / (1.0f + __expf(-x));
}
__device__ __forceinline__ float softplusf(float x) {
  return (x > 20.0f) ? x : log1pf(expf(x));
}
__device__ __forceinline__ u16 f2bf(float f) {   // RNE f32->bf16
  unsigned int u = __float_as_uint(f);
  u += 0x7FFFu + ((u >> 16) & 1u);
  return (u16)(u >> 16);
}
__device__ __forceinline__ float bf2f(u16 h) {
  return __uint_as_float(((unsigned int)h) << 16);
}

union F4 { float4 v; float a[4]; };

// VALU-only 16-lane rotation-add (DPP row_ror). All lanes end with the sum.
template<int CTRL>
__device__ __forceinline__ float dpp_add(float x) {
  union { float f; int i; } u, r;
  u.f = x;
  r.i = __builtin_amdgcn_update_dpp(0, u.i, CTRL, 0xF, 0xF, true);
  return x + r.f;
}

// ---------------------------------------------------------------------------
// K0: weight prep. winb/woutb = bf16 GEMM weights. Wcomb (224x192) =
// [dtw @ xpw[:24] ; xpw[24:56]] split into hi/lo bf16 for split-bf16 MFMA.
__global__ void k_prep(const float* __restrict__ xpw, const float* __restrict__ dtw,
                       const float* __restrict__ inw, const float* __restrict__ outw,
                       u16* __restrict__ winb, u16* __restrict__ woutb,
                       u16* __restrict__ wc_hi, u16* __restrict__ wc_lo) {
  int t = threadIdx.x + blockIdx.x * blockDim.x;
  int stride = blockDim.x * gridDim.x;
  for (int i = t; i < DIMQ * DIMQ; i += stride) {
    winb[i]  = f2bf(inw[i]);
    woutb[i] = f2bf(outw[i]);
  }
  for (int i = t; i < 224 * 192; i += stride) {
    const int r = i / 192, k = i % 192;
    float v;
    if (r < 192) {            // W_eff[r][k] = sum_q dtw[r][q]*xpw[q][k]
      float s = 0.0f;
      for (int q = 0; q < RKQ; ++q) s = fmaf(dtw[r * RKQ + q], xpw[q * 192 + k], s);
      v = s;
    } else {
      v = xpw[(24 + (r - 192)) * 192 + k];
    }
    const u16 hi = f2bf(v);
    wc_hi[i] = hi;
    wc_lo[i] = f2bf(v - bf2f(hi));
  }
}

// ---------------------------------------------------------------------------
// K1: in_proj GEMM via MFMA bf16, pipelined staging (prefetch next K-chunk
// before the MFMA of the current one). Output channel-major xp_t.
__launch_bounds__(256)
__global__ void k_inproj(const float* __restrict__ x, const u16* __restrict__ wbf,
                         const float* __restrict__ bias, float* __restrict__ xp_t) {
  __shared__ __align__(16) char smem[33792];
  u16 (*As)[72] = (u16(*)[72])smem;                 // [128][72]
  u16 (*Bs)[72] = (u16(*)[72])(smem + 18432);       // [64][72]
  const int t = threadIdx.x;
  const int m0 = blockIdx.x * BM;
  const int n0 = blockIdx.y * BN;
  const int lane = t & 63, wid = t >> 6;
  const int wm = wid >> 1, wn = wid & 1;
  const int lr = lane & 15, lg = lane >> 4;
  const int ar0 = t >> 4, akq = (t & 15) * 4;       // A staging: row += i*16
  const int br0 = t >> 3, bkq = (t & 7) * 8;        // B staging: row += i*32
  f32x4 acc[4][2];
#pragma unroll
  for (int i = 0; i < 4; ++i)
#pragma unroll
    for (int j = 0; j < 2; ++j) acc[i][j] = (f32x4){0.f, 0.f, 0.f, 0.f};

  float4 a_ld[8];
  u16x8 b_ld[2];
#define IN_LOAD(KC) { \
  _Pragma("unroll") \
  for (int i = 0; i < 8; ++i) \
    a_ld[i] = *(const float4*)&x[(size_t)(m0 + ar0 + i * 16) * 384 + (KC) * BK + akq]; \
  _Pragma("unroll") \
  for (int i = 0; i < 2; ++i) \
    b_ld[i] = *(const u16x8*)&wbf[(size_t)(n0 + br0 + i * 32) * 384 + (KC) * BK + bkq]; \
}
  IN_LOAD(0);
  for (int kc = 0; kc < 6; ++kc) {
    __syncthreads();
#pragma unroll
    for (int i = 0; i < 8; ++i) {
      u16x4 p;
      p.x = f2bf(a_ld[i].x); p.y = f2bf(a_ld[i].y);
      p.z = f2bf(a_ld[i].z); p.w = f2bf(a_ld[i].w);
      *(u16x4*)&As[ar0 + i * 16][akq] = p;
    }
#pragma unroll
    for (int i = 0; i < 2; ++i)
      *(u16x8*)&Bs[br0 + i * 32][bkq] = b_ld[i];
    __syncthreads();
    if (kc < 5) IN_LOAD(kc + 1);        // prefetch: in flight during MFMA
#pragma unroll
    for (int kh = 0; kh < BK; kh += 32) {
      s16x8 af[4], bf[2];
#pragma unroll
      for (int mi = 0; mi < 4; ++mi)
        af[mi] = *(const s16x8*)&As[wm * 64 + mi * 16 + lr][kh + lg * 8];
#pragma unroll
      for (int ni = 0; ni < 2; ++ni)
        bf[ni] = *(const s16x8*)&Bs[wn * 32 + ni * 16 + lr][kh + lg * 8];
#pragma unroll
      for (int mi = 0; mi < 4; ++mi)
#pragma unroll
        for (int ni = 0; ni < 2; ++ni)
          acc[mi][ni] = __builtin_amdgcn_mfma_f32_16x16x32_bf16(af[mi], bf[ni], acc[mi][ni], 0, 0, 0);
    }
  }
#undef IN_LOAD
  __syncthreads();
  float (*T)[132] = (float(*)[132])smem;            // [64][132]
#pragma unroll
  for (int mi = 0; mi < 4; ++mi)
#pragma unroll
    for (int ni = 0; ni < 2; ++ni) {
      const int c_loc = wn * 32 + ni * 16 + lr;
      const int m_loc = wm * 64 + mi * 16 + lg * 4;
      *(f32x4*)&T[c_loc][m_loc] = acc[mi][ni];
    }
  __syncthreads();
  const int s = m0 >> 11, p0 = m0 & 2047;
#pragma unroll
  for (int i = 0; i < 8; ++i) {
    const int idx = t + i * 256;
    const int c = idx >> 5, pq = (idx & 31) * 4;
    float4 v = *(const float4*)&T[c][pq];
    const float bv = bias[n0 + c];
    v.x += bv; v.y += bv; v.z += bv; v.w += bv;
    *(float4*)&xp_t[((size_t)s * 384 + n0 + c) * 2048 + p0 + pq] = v;
  }
}

// ---------------------------------------------------------------------------
// K2: grouped conv (k=3, SAME) + SiLU.
__global__ void k_conv(const float* __restrict__ xp_t, const float* __restrict__ cw,
                       const float* __restrict__ cb, float* __restrict__ xc) {
  const int idx = blockIdx.x * 256 + threadIdx.x;
  const int p = idx & 2047;
  const int sd = idx >> 11;
  const int d = sd % DIQ, s = sd / DIQ;
  const float* r0 = &xp_t[((size_t)s * 384 + 2 * d) * 2048];
  const float* r1 = r0 + 2048;
  const float w00 = cw[d * 6 + 0], w01 = cw[d * 6 + 1], w02 = cw[d * 6 + 2];
  const float w10 = cw[d * 6 + 3], w11 = cw[d * 6 + 4], w12 = cw[d * 6 + 5];
  float acc = cb[d];
  if (p > 0)    acc += w00 * r0[p - 1] + w10 * r1[p - 1];
  acc += w01 * r0[p] + w11 * r1[p];
  if (p < 2047) acc += w02 * r0[p + 1] + w12 * r1[p + 1];
  xc[idx] = siluf(acc);
}

// ---------------------------------------------------------------------------
// K3: fused x_proj + dt_proj as ONE split-bf16 MFMA GEMM.
__launch_bounds__(256)
__global__ void k_xproj(const float* __restrict__ xc, const u16* __restrict__ wc_hi,
                        const u16* __restrict__ wc_lo, const float* __restrict__ dtb,
                        float* __restrict__ delta, float* __restrict__ bc) {
  __shared__ u16 Ah[224][40];
  __shared__ u16 Al[224][40];
  __shared__ u16 Bh[64][40];
  __shared__ u16 Bl[64][40];
  const int t = threadIdx.x;
  const int lane = t & 63, w = t >> 6;
  const int ln = lane & 15, lg = lane >> 4;
  const int blk = blockIdx.x;                 // 0..383
  const int s = blk >> 5, l0 = (blk & 31) * 64;
  f32x4 acc[14];
#pragma unroll
  for (int mi = 0; mi < 14; ++mi) acc[mi] = (f32x4){0.f, 0.f, 0.f, 0.f};

  for (int kc = 0; kc < 192; kc += 32) {
    u16x8 wah[4], wal[4];
#pragma unroll
    for (int i = 0; i < 4; ++i) {
      const int idx = t + i * 256;
      if (idx < 896) {
        const int r = idx >> 2, kg = (idx & 3) * 8;
        wah[i] = *(const u16x8*)&wc_hi[(size_t)r * 192 + kc + kg];
        wal[i] = *(const u16x8*)&wc_lo[(size_t)r * 192 + kc + kg];
      }
    }
    float4 uld[2];
#pragma unroll
    for (int i = 0; i < 2; ++i) {
      const int idx = t + i * 256;
      const int k = idx >> 4, lq = (idx & 15) * 4;
      uld[i] = *(const float4*)&xc[((size_t)s * 192 + kc + k) * 2048 + l0 + lq];
    }
    __syncthreads();
#pragma unroll
    for (int i = 0; i < 4; ++i) {
      const int idx = t + i * 256;
      if (idx < 896) {
        const int r = idx >> 2, kg = (idx & 3) * 8;
        *(u16x8*)&Ah[r][kg] = wah[i];
        *(u16x8*)&Al[r][kg] = wal[i];
      }
    }
#pragma unroll
    for (int i = 0; i < 2; ++i) {
      const int idx = t + i * 256;
      const int k = idx >> 4, lq = (idx & 15) * 4;
      F4 v; v.v = uld[i];
#pragma unroll
      for (int j = 0; j < 4; ++j) {
        const float f = v.a[j];
        const u16 hi = f2bf(f);
        Bh[lq + j][k] = hi;
        Bl[lq + j][k] = f2bf(f - bf2f(hi));
      }
    }
    __syncthreads();
    const s16x8 bh = *(const s16x8*)&Bh[w * 16 + ln][lg * 8];
    const s16x8 bl = *(const s16x8*)&Bl[w * 16 + ln][lg * 8];
#pragma unroll
    for (int mi = 0; mi < 14; ++mi) {
      const s16x8 ah = *(const s16x8*)&Ah[mi * 16 + ln][lg * 8];
      const s16x8 al = *(const s16x8*)&Al[mi * 16 + ln][lg * 8];
      acc[mi] = __builtin_amdgcn_mfma_f32_16x16x32_bf16(ah, bh, acc[mi], 0, 0, 0);
      acc[mi] = __builtin_amdgcn_mfma_f32_16x16x32_bf16(al, bh, acc[mi], 0, 0, 0);
      acc[mi] = __builtin_amdgcn_mfma_f32_16x16x32_bf16(ah, bl, acc[mi], 0, 0, 0);
    }
    __syncthreads();
  }
  const int l = l0 + w * 16 + ln;
#pragma unroll
  for (int mi = 0; mi < 12; ++mi) {
    const int r0 = mi * 16 + lg * 4;
#pragma unroll
    for (int j = 0; j < 4; ++j) {
      const int r = r0 + j;
      delta[((size_t)s * 192 + r) * 2048 + l] = softplusf(acc[mi][j] + dtb[r]);
    }
  }
#pragma unroll
  for (int mi = 12; mi < 14; ++mi) {
    const int rr = (mi - 12) * 16 + lg * 4;
    float4 v;
    v.x = acc[mi][0]; v.y = acc[mi][1]; v.z = acc[mi][2]; v.w = acc[mi][3];
    *(float4*)&bc[((size_t)s * 2048 + l) * 32 + rr] = v;
  }
}

// ---------------------------------------------------------------------------
// scanA (both directions in one block): per-chunk gains and zero-init end
// states. Physical chunk tcp; fwd chunk idx = tcp, bwd chunk idx = 15-tcp.
// G = exp(a*sum(delta)) is computed from the shared S.
__launch_bounds__(256)
__global__ void k_scanA(const float* __restrict__ delta, const float* __restrict__ xc,
                        const float* __restrict__ bc, const float* __restrict__ A_log,
                        const float* __restrict__ Ab_log,
                        float* __restrict__ G, float* __restrict__ hc) {
  __shared__ float dch[16][132];
  __shared__ float uch[16][132];
  __shared__ float bsn[16][132];   // B transposed: [n][l]
  const int t = threadIdx.x;
  const int dl = t >> 4, n = t & 15;
  const int dg = blockIdx.x;
  const int s  = blockIdx.y;
  const int tcp = blockIdx.z;
  const int d = dg * 16 + dl;
  const int base_l = CLEN * tcp;
  const float af = -__expf(A_log[d * 16 + n]);
  const float ab = -__expf(Ab_log[d * 16 + n]);

  const size_t rb = ((size_t)s * 192 + dg * 16) * 2048 + base_l;
#pragma unroll
  for (int it = 0; it < 2; ++it) {
    const int i = t + it * 256;
    const int row = i >> 5, c4 = (i & 31) * 4;
    *(float4*)&dch[row][c4] = *(const float4*)&delta[rb + (size_t)row * 2048 + c4];
    *(float4*)&uch[row][c4] = *(const float4*)&xc[rb + (size_t)row * 2048 + c4];
  }
  const size_t bb = ((size_t)s * 2048 + base_l) * 32;
#pragma unroll
  for (int it = 0; it < 2; ++it) {
    const int i = t + it * 256;
    const int l = i >> 2, nq = (i & 3) * 4;
    F4 v; v.v = *(const float4*)&bc[bb + (size_t)l * 32 + nq];
#pragma unroll
    for (int k = 0; k < 4; ++k) bsn[nq + k][l] = v.a[k];
  }
  __syncthreads();
  float hf = 0.0f, hb = 0.0f, S = 0.0f;
#pragma unroll 4
  for (int qx = 0; qx < 32; ++qx) {
    const int lqf = qx * 4;
    const int lqb = (31 - qx) * 4;
    F4 d4f, u4f, b4f, d4b, u4b, b4b;
    d4f.v = *(const float4*)&dch[dl][lqf];
    u4f.v = *(const float4*)&uch[dl][lqf];
    b4f.v = *(const float4*)&bsn[n][lqf];
    d4b.v = *(const float4*)&dch[dl][lqb];
    u4b.v = *(const float4*)&uch[dl][lqb];
    b4b.v = *(const float4*)&bsn[n][lqb];
#pragma unroll
    for (int jj = 0; jj < 4; ++jj) {
      { const float dlt = d4f.a[jj];
        hf = fmaf(__expf(af * dlt), hf, dlt * u4f.a[jj] * b4f.a[jj]);
        S += dlt; }
      { const int j = 3 - jj;
        const float dlt = d4b.a[j];
        hb = fmaf(__expf(ab * dlt), hb, dlt * u4b.a[j] * b4b.a[j]); }
    }
  }
  const int dn = d * 16 + n;
  const size_t idx_f = ((size_t)(s * 2 + 0) * NCHK + tcp) * 3072 + dn;
  const size_t idx_b = ((size_t)(s * 2 + 1) * NCHK + (NCHK - 1 - tcp)) * 3072 + dn;
  G[idx_f] = __expf(af * S);  hc[idx_f] = hf;
  G[idx_b] = __expf(ab * S);  hc[idx_b] = hb;
}

// scanB: sequential carry scan over chunks; hc[tc] := h_in(tc) (in place).
__global__ void k_scanB(const float* __restrict__ G, float* __restrict__ hc) {
  const int gid = blockIdx.x * 256 + threadIdx.x;
  const int sd2 = gid / 3072;
  const int dn = gid % 3072;
  float h = 0.0f;
#pragma unroll
  for (int tc = 0; tc < NCHK; ++tc) {
    const size_t idx = ((size_t)sd2 * NCHK + tc) * 3072 + dn;
    const float g = G[idx];
    const float he = hc[idx];
    hc[idx] = h;
    h = fmaf(g, h, he);
  }
}

// scanC (both directions): re-run chunk seeded with h_in, emit yf and yb from
// a single LDS staging (DPP rotation reduce over the 16 n lanes).
__launch_bounds__(256)
__global__ void k_scanC(const float* __restrict__ delta, const float* __restrict__ xc,
                        const float* __restrict__ bc, const float* __restrict__ A_log,
                        const float* __restrict__ Ab_log, const float* __restrict__ hc,
                        float* __restrict__ yf, float* __restrict__ yb) {
  __shared__ float dch[16][132];
  __shared__ float uch[16][132];
  __shared__ float bsn[16][132];
  __shared__ float csn[16][132];
  const int t = threadIdx.x;
  const int dl = t >> 4, n = t & 15;
  const int dg = blockIdx.x;
  const int s  = blockIdx.y;
  const int tcp = blockIdx.z;
  const int d = dg * 16 + dl;
  const int base_l = CLEN * tcp;
  const float af = -__expf(A_log[d * 16 + n]);
  const float ab = -__expf(Ab_log[d * 16 + n]);

  const size_t rb = ((size_t)s * 192 + dg * 16) * 2048 + base_l;
#pragma unroll
  for (int it = 0; it < 2; ++it) {
    const int i = t + it * 256;
    const int row = i >> 5, c4 = (i & 31) * 4;
    *(float4*)&dch[row][c4] = *(const float4*)&delta[rb + (size_t)row * 2048 + c4];
    *(float4*)&uch[row][c4] = *(const float4*)&xc[rb + (size_t)row * 2048 + c4];
  }
  const size_t bb = ((size_t)s * 2048 + base_l) * 32;
#pragma unroll
  for (int it = 0; it < 4; ++it) {
    const int i = t + it * 256;
    const int l = i >> 3, cq = (i & 7) * 4;
    F4 v; v.v = *(const float4*)&bc[bb + (size_t)l * 32 + cq];
    if (cq < 16) {
#pragma unroll
      for (int k = 0; k < 4; ++k) bsn[cq + k][l] = v.a[k];
    } else {
#pragma unroll
      for (int k = 0; k < 4; ++k) csn[cq - 16 + k][l] = v.a[k];
    }
  }
  const int dn = d * 16 + n;
  const size_t idx_f = ((size_t)(s * 2 + 0) * NCHK + tcp) * 3072 + dn;
  const size_t idx_b = ((size_t)(s * 2 + 1) * NCHK + (NCHK - 1 - tcp)) * 3072 + dn;
  float hf = hc[idx_f];
  float hb = hc[idx_b];
  __syncthreads();
  float* yrf = &yf[((size_t)s * 192 + d) * 2048 + base_l];
  float* yrb = &yb[((size_t)s * 192 + d) * 2048 + base_l];
#pragma unroll 2
  for (int ww = 0; ww < 8; ++ww) {
    const int wf = ww, wb = 7 - ww;
    float ykf = 0.0f, ykb = 0.0f;
#pragma unroll
    for (int qq = 0; qq < 4; ++qq) {
      const int qf = qq, qb = 3 - qq;
      const int lqf = wf * 16 + qf * 4;
      const int lqb = wb * 16 + qb * 4;
      F4 d4f, u4f, b4f, c4f, d4b, u4b, b4b, c4b;
      d4f.v = *(const float4*)&dch[dl][lqf];
      u4f.v = *(const float4*)&uch[dl][lqf];
      b4f.v = *(const float4*)&bsn[n][lqf];
      c4f.v = *(const float4*)&csn[n][lqf];
      d4b.v = *(const float4*)&dch[dl][lqb];
      u4b.v = *(const float4*)&uch[dl][lqb];
      b4b.v = *(const float4*)&bsn[n][lqb];
      c4b.v = *(const float4*)&csn[n][lqb];
#pragma unroll
      for (int jj = 0; jj < 4; ++jj) {
        { const int j = jj;
          const float dlt = d4f.a[j];
          hf = fmaf(__expf(af * dlt), hf, dlt * u4f.a[j] * b4f.a[j]);
          float yv = hf * c4f.a[j];
          yv = dpp_add<0x128>(yv);
          yv = dpp_add<0x124>(yv);
          yv = dpp_add<0x122>(yv);
          yv = dpp_add<0x121>(yv);
          ykf = (qf * 4 + j == n) ? yv : ykf; }
        { const int j = 3 - jj;
          const float dlt = d4b.a[j];
          hb = fmaf(__expf(ab * dlt), hb, dlt * u4b.a[j] * b4b.a[j]);
          float yv = hb * c4b.a[j];
          yv = dpp_add<0x128>(yv);
          yv = dpp_add<0x124>(yv);
          yv = dpp_add<0x122>(yv);
          yv = dpp_add<0x121>(yv);
          ykb = (qb * 4 + j == n) ? yv : ykb; }
      }
    }
    yrf[wf * 16 + n] = ykf;
    yrb[wb * 16 + n] = ykb;
  }
}

// ---------------------------------------------------------------------------
// K4b: combine fwd+bwd+2Du || z, transpose to position-major bf16 A-buffer.
#define SWC(l) (((l >> 2) & 7) << 3)
__launch_bounds__(256)
__global__ void k_combine(const float* __restrict__ yf, const float* __restrict__ yb,
                          const float* __restrict__ xc, const float* __restrict__ Dvec,
                          u16* __restrict__ Abuf) {
  __shared__ u16 T[64][72];
  const int t = threadIdx.x;
  const int cg = blockIdx.x;                 // 0..5
  const int s  = blockIdx.y;                 // 0..11
  const int l0 = blockIdx.z * 64;            // 0..31 chunks
  const int c0 = (cg < 3 ? cg : cg - 3) * 64;
#pragma unroll
  for (int i = 0; i < 4; ++i) {
    const int idx = t + i * 256;             // 1024
    const int cr = idx >> 4, lq = (idx & 15) * 4;
    const size_t off = ((size_t)s * 192 + c0 + cr) * 2048 + l0 + lq;
    F4 v;
    if (cg < 3) {
      F4 f, g, u;
      f.v = *(const float4*)&yf[off];
      g.v = *(const float4*)&yb[off];
      u.v = *(const float4*)&xc[off];
      const float dv2 = 2.0f * Dvec[c0 + cr];
#pragma unroll
      for (int j = 0; j < 4; ++j) v.a[j] = f.a[j] + g.a[j] + dv2 * u.a[j];
    } else {
      v.v = *(const float4*)&xc[off];
    }
#pragma unroll
    for (int j = 0; j < 4; ++j) {
      const int l = lq + j;
      T[l][cr ^ SWC(l)] = f2bf(v.a[j]);
    }
  }
  __syncthreads();
  const int ccol = (cg < 3) ? cg * 64 : 192 + (cg - 3) * 64;
#pragma unroll
  for (int i = 0; i < 2; ++i) {
    const int idx = t + i * 256;             // 512
    const int l = idx >> 3, cq = (idx & 7) * 8;
    const u16x8 v = *(const u16x8*)&T[l][cq ^ SWC(l)];
    *(u16x8*)&Abuf[((size_t)s * 2048 + l0 + l) * 384 + ccol + cq] = v;
  }
}

// ---------------------------------------------------------------------------
// K5: out_proj GEMM via MFMA bf16, pipelined staging.
__launch_bounds__(256)
__global__ void k_outproj(const u16* __restrict__ Abuf, const u16* __restrict__ wbf,
                          const float* __restrict__ bias, float* __restrict__ out) {
  __shared__ __align__(16) char smem[34816];
  u16 (*As)[72] = (u16(*)[72])smem;                 // [128][72]
  u16 (*Bs)[72] = (u16(*)[72])(smem + 18432);       // [64][72]
  const int t = threadIdx.x;
  const int m0 = blockIdx.x * BM;
  const int n0 = blockIdx.y * BN;
  const int lane = t & 63, wid = t >> 6;
  const int wm = wid >> 1, wn = wid & 1;
  const int lr = lane & 15, lg = lane >> 4;
  const int ar0 = t >> 3, akq = (t & 7) * 8;        // A: row += i*32
  const int br0 = t >> 3, bkq = (t & 7) * 8;        // B: row += i*32
  f32x4 acc[4][2];
#pragma unroll
  for (int i = 0; i < 4; ++i)
#pragma unroll
    for (int j = 0; j < 2; ++j) acc[i][j] = (f32x4){0.f, 0.f, 0.f, 0.f};

  u16x8 a_ld[4], b_ld[2];
#define OUT_LOAD(KC) { \
  _Pragma("unroll") \
  for (int i = 0; i < 4; ++i) \
    a_ld[i] = *(const u16x8*)&Abuf[(size_t)(m0 + ar0 + i * 32) * 384 + (KC) * BK + akq]; \
  _Pragma("unroll") \
  for (int i = 0; i < 2; ++i) \
    b_ld[i] = *(const u16x8*)&wbf[(size_t)(n0 + br0 + i * 32) * 384 + (KC) * BK + bkq]; \
}
  OUT_LOAD(0);
  for (int kc = 0; kc < 6; ++kc) {
    __syncthreads();
#pragma unroll
    for (int i = 0; i < 4; ++i)
      *(u16x8*)&As[ar0 + i * 32][akq] = a_ld[i];
#pragma unroll
    for (int i = 0; i < 2; ++i)
      *(u16x8*)&Bs[br0 + i * 32][bkq] = b_ld[i];
    __syncthreads();
    if (kc < 5) OUT_LOAD(kc + 1);       // prefetch during MFMA
#pragma unroll
    for (int kh = 0; kh < BK; kh += 32) {
      s16x8 af[4], bf[2];
#pragma unroll
      for (int mi = 0; mi < 4; ++mi)
        af[mi] = *(const s16x8*)&As[wm * 64 + mi * 16 + lr][kh + lg * 8];
#pragma unroll
      for (int ni = 0; ni < 2; ++ni)
        bf[ni] = *(const s16x8*)&Bs[wn * 32 + ni * 16 + lr][kh + lg * 8];
#pragma unroll
      for (int mi = 0; mi < 4; ++mi)
#pragma unroll
        for (int ni = 0; ni < 2; ++ni)
          acc[mi][ni] = __builtin_amdgcn_mfma_f32_16x16x32_bf16(af[mi], bf[ni], acc[mi][ni], 0, 0, 0);
    }
  }
#undef OUT_LOAD
  __syncthreads();
  float (*T)[68] = (float(*)[68])smem;              // [128][68]
#pragma unroll
  for (int mi = 0; mi < 4; ++mi)
#pragma unroll
    for (int ni = 0; ni < 2; ++ni) {
      const int c_loc = wn * 32 + ni * 16 + lr;
      const int m_loc = wm * 64 + mi * 16 + lg * 4;
#pragma unroll
      for (int r = 0; r < 4; ++r) T[m_loc + r][c_loc] = acc[mi][ni][r];
    }
  __syncthreads();
#pragma unroll
  for (int i = 0; i < 8; ++i) {
    const int idx = t + i * 256;
    const int m = idx >> 4, cq = (idx & 15) * 4;
    float4 v = *(const float4*)&T[m][cq];
    const float4 bb = *(const float4*)&bias[n0 + cq];
    v.x += bb.x; v.y += bb.y; v.z += bb.z; v.w += bb.w;
    *(float4*)&out[(size_t)(m0 + m) * 384 + n0 + cq] = v;
  }
}

// ---------------------------------------------------------------------------
extern "C" void kernel_launch(void* const* d_in, const int* in_sizes, int n_in,
                              void* d_out, int out_size, void* d_ws, size_t ws_size,
                              hipStream_t stream) {
  const float* x     = (const float*)d_in[0];
  const float* inw   = (const float*)d_in[1];
  const float* inb   = (const float*)d_in[2];
  const float* convw = (const float*)d_in[3];
  const float* convb = (const float*)d_in[4];
  const float* alog  = (const float*)d_in[5];
  const float* ablog = (const float*)d_in[6];
  const float* Dv    = (const float*)d_in[7];
  const float* xpw   = (const float*)d_in[8];
  const float* dtw   = (const float*)d_in[9];
  const float* dtb   = (const float*)d_in[10];
  const float* outw  = (const float*)d_in[11];
  const float* outb  = (const float*)d_in[12];
  float* out = (float*)d_out;

  float* ws = (float*)d_ws;
  float* xp_t  = ws;                       // 9437184
  float* xc    = xp_t + 9437184;           // 4718592
  float* delta = xc + 4718592;             // 4718592
  float* bc    = delta + 4718592;          // 786432
  float* G     = bc + 786432;              // 1179648
  float* hc    = G + 1179648;              // 1179648
  u16*   winb  = (u16*)(hc + 1179648);     // 147456 u16
  u16*   woutb = winb + 147456;            // 147456 u16
  u16*   wc_hi = woutb + 147456;           // 43008 u16
  u16*   wc_lo = wc_hi + 43008;            // 43008 u16
  // yf/yb alias xp_t (dead after conv); Abuf aliases delta (dead after scanC)
  float* yf = xp_t;
  float* yb = xp_t + 4718592;
  u16*   Abuf = (u16*)delta;

  hipLaunchKernelGGL(k_prep,    dim3(96),         dim3(256), 0, stream, xpw, dtw, inw, outw, winb, woutb, wc_hi, wc_lo);
  hipLaunchKernelGGL(k_inproj,  dim3(192, 6),     dim3(256), 0, stream, x, winb, inb, xp_t);
  hipLaunchKernelGGL(k_conv,    dim3(18432),      dim3(256), 0, stream, xp_t, convw, convb, xc);
  hipLaunchKernelGGL(k_xproj,   dim3(384),        dim3(256), 0, stream, xc, wc_hi, wc_lo, dtb, delta, bc);
  hipLaunchKernelGGL(k_scanA,   dim3(12, 12, 16), dim3(256), 0, stream, delta, xc, bc, alog, ablog, G, hc);
  hipLaunchKernelGGL(k_scanB,   dim3(288),        dim3(256), 0, stream, G, hc);
  hipLaunchKernelGGL(k_scanC,   dim3(12, 12, 16), dim3(256), 0, stream, delta, xc, bc, alog, ablog, hc, yf, yb);
  hipLaunchKernelGGL(k_combine, dim3(6, 12, 32),  dim3(256), 0, stream, yf, yb, xc, Dv, Abuf);
  hipLaunchKernelGGL(k_outproj, dim3(192, 6),     dim3(256), 0, stream, Abuf, woutb, outb, out);
}